// Round 2
// baseline (3973.017 us; speedup 1.0000x reference)
//
#include <hip/hip_runtime.h>
#include <hip/hip_bf16.h>
#include <math.h>

#define DD   43      // hidden size
#define RR   172     // 4*DD gate rows
#define TT   2048
#define BB   256
#define FEAT 8
#define NH1  30
#define NH2  20

using bf16 = __hip_bfloat16;

__device__ __forceinline__ float ldv(const float* p)  { return *p; }
__device__ __forceinline__ float ldv(const bf16* p)   { return __bfloat162float(*p); }
__device__ __forceinline__ void  stv(float* p, float v) { *p = v; }
__device__ __forceinline__ void  stv(bf16* p,  float v) { *p = __float2bfloat16(v); }

__device__ __forceinline__ float sig_(float x) {
    return 1.0f / (1.0f + __expf(-x));
}
__device__ __forceinline__ float tanh_(float x) {
    float ax = fabsf(x);
    float e  = __expf(-2.0f * ax);
    float t  = (1.0f - e) / (1.0f + e);
    return x < 0.0f ? -t : t;
}

// ---- prep: fold input projection into layer-1 weights; combine biases ----
// w_eff1[(dir*RR+r)*FEAT+k] = sum_d w_ih1[dir][r][d] * w_proj[d][k]
// b_eff1[dir*RR+r]          = b_ih1+b_hh1 + sum_d w_ih1[r][d]*b_proj[d]
// b_eff2[dir*RR+r]          = b_ih2 + b_hh2
__global__ void prep_kernel(const float* __restrict__ wp, const float* __restrict__ bp,
                            const float* __restrict__ w_ih1f, const float* __restrict__ b_ih1f, const float* __restrict__ b_hh1f,
                            const float* __restrict__ w_ih1b, const float* __restrict__ b_ih1b, const float* __restrict__ b_hh1b,
                            const float* __restrict__ b_ih2f, const float* __restrict__ b_hh2f,
                            const float* __restrict__ b_ih2b, const float* __restrict__ b_hh2b,
                            float* __restrict__ w_eff1, float* __restrict__ b_eff1,
                            float* __restrict__ b_eff2) {
    int tid = blockIdx.x * blockDim.x + threadIdx.x;
    if (tid < 2 * RR) {
        int dir = tid / RR, r = tid % RR;
        const float* w_ih = dir ? w_ih1b : w_ih1f;
        const float* bi   = dir ? b_ih1b : b_ih1f;
        const float* bh   = dir ? b_hh1b : b_hh1f;
        const float* row  = w_ih + (long)r * DD;
        float acc[FEAT];
#pragma unroll
        for (int k = 0; k < FEAT; ++k) acc[k] = 0.0f;
        float bacc = bi[r] + bh[r];
        for (int d = 0; d < DD; ++d) {
            float w = row[d];
            bacc = fmaf(w, bp[d], bacc);
#pragma unroll
            for (int k = 0; k < FEAT; ++k) acc[k] = fmaf(w, wp[d * FEAT + k], acc[k]);
        }
#pragma unroll
        for (int k = 0; k < FEAT; ++k) w_eff1[(long)tid * FEAT + k] = acc[k];
        b_eff1[tid] = bacc;
    } else if (tid < 4 * RR) {
        int j = tid - 2 * RR;
        int dir = j / RR, r = j % RR;
        b_eff2[j] = dir ? (b_ih2b[r] + b_hh2b[r]) : (b_ih2f[r] + b_hh2f[r]);
    }
}

// ---- one bidirectional LSTM layer: one block per (dir,batch) chain ----
// thread r < RR owns gate-row r, weights in VGPRs. Two barriers per step.
template <int KI, typename TIN, typename TOUT>
__global__ __launch_bounds__(192) void lstm_kernel(
        const TIN* __restrict__ in,        // [B][T][KI]
        const float* __restrict__ w_ih_f,  // [RR][KI]
        const float* __restrict__ w_hh_f,  // [RR][DD]
        const float* __restrict__ bias_f,  // [RR] (combined)
        const float* __restrict__ w_ih_b,
        const float* __restrict__ w_hh_b,
        const float* __restrict__ bias_b,
        TOUT* __restrict__ out)            // [B][T][2*DD]
{
    const int bid = blockIdx.x;
    const int dir = bid & 1;       // 0 = fwd, 1 = bwd
    const int b   = bid >> 1;
    const int tid = threadIdx.x;

    const float* w_ih = dir ? w_ih_b : w_ih_f;
    const float* w_hh = dir ? w_hh_b : w_hh_f;
    const float* bias = dir ? bias_b : bias_f;

    __shared__ float xbuf[2][KI];
    __shared__ float hbuf[DD];
    __shared__ float zbuf[RR];

    float wi[KI];
    float wh[DD];
    float bsum = 0.0f, c = 0.0f;
    if (tid < RR) {
        const float* wr = w_ih + (long)tid * KI;
#pragma unroll
        for (int k = 0; k < KI; ++k) wi[k] = wr[k];
        const float* hr = w_hh + (long)tid * DD;
#pragma unroll
        for (int k = 0; k < DD; ++k) wh[k] = hr[k];
        bsum = bias[tid];
    }

    const long t0   = dir ? (TT - 1) : 0;
    const int  step = dir ? -1 : 1;

    if (tid < DD) hbuf[tid] = 0.0f;
    float xnext = 0.0f;
    if (tid < KI) xnext = ldv(&in[((long)b * TT + t0) * KI + tid]);

    TOUT* outp = out + (long)b * TT * (2 * DD) + dir * DD;

    __syncthreads();

    long tcur = t0;
    for (int s = 0; s < TT; ++s) {
        if (tid < KI) xbuf[s & 1][tid] = xnext;
        __syncthreads();

        if (tid < RR) {
            float z = bsum;
            const float* xb = xbuf[s & 1];
#pragma unroll
            for (int k = 0; k < KI; ++k) z = fmaf(wi[k], xb[k], z);
#pragma unroll
            for (int k = 0; k < DD; ++k) z = fmaf(wh[k], hbuf[k], z);
            zbuf[tid] = z;
        }
        // prefetch next timestep's input (latency hidden under this step)
        long tnext = tcur + step;
        if (s + 1 < TT && tid < KI) xnext = ldv(&in[((long)b * TT + tnext) * KI + tid]);
        __syncthreads();

        if (tid < DD) {
            float zi = zbuf[tid];
            float zf = zbuf[tid + DD];
            float zg = zbuf[tid + 2 * DD];
            float zo = zbuf[tid + 3 * DD];
            float ig = sig_(zi), fg = sig_(zf), gg = tanh_(zg), og = sig_(zo);
            c = fmaf(fg, c, ig * gg);
            float h = og * tanh_(c);
            hbuf[tid] = h;
            stv(&outp[tcur * (2 * DD) + tid], h);
        }
        tcur = tnext;
    }
}

// ---- dense head: per (b,t): 86 -> 30 -> 20 -> 1 ----
template <typename TIN>
__global__ void head_kernel(const TIN* __restrict__ h2,   // [BT][2*DD]
                            const float* __restrict__ w1, const float* __restrict__ b1,
                            const float* __restrict__ w2, const float* __restrict__ b2,
                            const float* __restrict__ w3, const float* __restrict__ b3,
                            float* __restrict__ outp) {
    long bt = (long)blockIdx.x * blockDim.x + threadIdx.x;
    if (bt >= (long)BB * TT) return;
    float v[2 * DD];
    const TIN* src = h2 + bt * (2 * DD);
#pragma unroll
    for (int k = 0; k < 2 * DD; ++k) v[k] = ldv(&src[k]);

    float m1[NH1];
#pragma unroll
    for (int j = 0; j < NH1; ++j) {
        float a = b1[j];
        const float* w = w1 + j * (2 * DD);
#pragma unroll
        for (int k = 0; k < 2 * DD; ++k) a = fmaf(w[k], v[k], a);
        m1[j] = fmaxf(a, 0.0f);
    }
    float m2[NH2];
#pragma unroll
    for (int j = 0; j < NH2; ++j) {
        float a = b2[j];
        const float* w = w2 + j * NH1;
#pragma unroll
        for (int k = 0; k < NH1; ++k) a = fmaf(w[k], m1[k], a);
        m2[j] = fmaxf(a, 0.0f);
    }
    float a = b3[0];
#pragma unroll
    for (int k = 0; k < NH2; ++k) a = fmaf(w3[k], m2[k], a);
    outp[bt] = a;
}

extern "C" void kernel_launch(void* const* d_in, const int* in_sizes, int n_in,
                              void* d_out, int out_size, void* d_ws, size_t ws_size,
                              hipStream_t stream) {
    const float* x      = (const float*)d_in[0];
    const float* w_proj = (const float*)d_in[1];
    const float* b_proj = (const float*)d_in[2];
    const float* w_ih1f = (const float*)d_in[3];
    const float* w_hh1f = (const float*)d_in[4];
    const float* b_ih1f = (const float*)d_in[5];
    const float* b_hh1f = (const float*)d_in[6];
    const float* w_ih1b = (const float*)d_in[7];
    const float* w_hh1b = (const float*)d_in[8];
    const float* b_ih1b = (const float*)d_in[9];
    const float* b_hh1b = (const float*)d_in[10];
    const float* w_ih2f = (const float*)d_in[11];
    const float* w_hh2f = (const float*)d_in[12];
    const float* b_ih2f = (const float*)d_in[13];
    const float* b_hh2f = (const float*)d_in[14];
    const float* w_ih2b = (const float*)d_in[15];
    const float* w_hh2b = (const float*)d_in[16];
    const float* b_ih2b = (const float*)d_in[17];
    const float* b_hh2b = (const float*)d_in[18];
    const float* w_d1   = (const float*)d_in[19];
    const float* b_d1   = (const float*)d_in[20];
    const float* w_d2   = (const float*)d_in[21];
    const float* b_d2   = (const float*)d_in[22];
    const float* w_out  = (const float*)d_in[23];
    const float* b_out  = (const float*)d_in[24];
    (void)in_sizes; (void)n_in; (void)out_size;

    // --- workspace layout ---
    // small prep region (16 KB): w_eff1 [2*RR*FEAT] | b_eff1 [2*RR] | b_eff2 [2*RR]
    float* w_eff1 = (float*)d_ws;
    float* b_eff1 = w_eff1 + 2 * RR * FEAT;
    float* b_eff2 = b_eff1 + 2 * RR;
    char*  big    = (char*)d_ws + 16384;
    size_t avail  = ws_size > 16384 ? ws_size - 16384 : 0;

    const size_t n1 = (size_t)BB * TT * 2 * DD;        // elems of out1/out2
    const size_t f1 = n1 * sizeof(float);              // 180.4 MB
    const size_t h1 = n1 * sizeof(bf16);               // 90.2 MB

    // tier 0: out1 f32, out2 f32 (361 MB) | tier 1: f32+bf16 (271 MB) | tier 2: bf16+bf16 (181 MB)
    int tier;
    if      (avail >= f1 + f1) tier = 0;
    else if (avail >= f1 + h1) tier = 1;
    else                       tier = 2;

    prep_kernel<<<(4 * RR + 191) / 192, 192, 0, stream>>>(
        w_proj, b_proj,
        w_ih1f, b_ih1f, b_hh1f, w_ih1b, b_ih1b, b_hh1b,
        b_ih2f, b_hh2f, b_ih2b, b_hh2b,
        w_eff1, b_eff1, b_eff2);

    const float* weff_f = w_eff1;
    const float* weff_b = w_eff1 + (size_t)RR * FEAT;
    const float* be1_f  = b_eff1;
    const float* be1_b  = b_eff1 + RR;
    const float* be2_f  = b_eff2;
    const float* be2_b  = b_eff2 + RR;
    const int head_blocks = (int)(((long)BB * TT + 255) / 256);

    if (tier == 0) {
        float* out1 = (float*)big;
        float* out2 = (float*)(big + f1);
        lstm_kernel<FEAT, float, float><<<2 * BB, 192, 0, stream>>>(
            x, weff_f, w_hh1f, be1_f, weff_b, w_hh1b, be1_b, out1);
        lstm_kernel<2 * DD, float, float><<<2 * BB, 192, 0, stream>>>(
            out1, w_ih2f, w_hh2f, be2_f, w_ih2b, w_hh2b, be2_b, out2);
        head_kernel<float><<<head_blocks, 256, 0, stream>>>(
            out2, w_d1, b_d1, w_d2, b_d2, w_out, b_out, (float*)d_out);
    } else if (tier == 1) {
        float* out1 = (float*)big;
        bf16*  out2 = (bf16*)(big + f1);
        lstm_kernel<FEAT, float, float><<<2 * BB, 192, 0, stream>>>(
            x, weff_f, w_hh1f, be1_f, weff_b, w_hh1b, be1_b, out1);
        lstm_kernel<2 * DD, float, bf16><<<2 * BB, 192, 0, stream>>>(
            out1, w_ih2f, w_hh2f, be2_f, w_ih2b, w_hh2b, be2_b, out2);
        head_kernel<bf16><<<head_blocks, 256, 0, stream>>>(
            out2, w_d1, b_d1, w_d2, b_d2, w_out, b_out, (float*)d_out);
    } else {
        bf16* out1 = (bf16*)big;
        bf16* out2 = (bf16*)(big + h1);
        lstm_kernel<FEAT, float, bf16><<<2 * BB, 192, 0, stream>>>(
            x, weff_f, w_hh1f, be1_f, weff_b, w_hh1b, be1_b, out1);
        lstm_kernel<2 * DD, bf16, bf16><<<2 * BB, 192, 0, stream>>>(
            out1, w_ih2f, w_hh2f, be2_f, w_ih2b, w_hh2b, be2_b, out2);
        head_kernel<bf16><<<head_blocks, 256, 0, stream>>>(
            out2, w_d1, b_d1, w_d2, b_d2, w_out, b_out, (float*)d_out);
    }
}

// Round 3
// 3261.656 us; speedup vs baseline: 1.2181x; 1.2181x over previous
//
#include <hip/hip_runtime.h>
#include <hip/hip_bf16.h>
#include <math.h>

#define DD   43      // hidden size
#define RR   172     // 4*DD gate rows
#define TT   2048
#define BB   256
#define FEAT 8
#define NH1  30
#define NH2  20

using bf16 = __hip_bfloat16;

__device__ __forceinline__ float ldv(const float* p)  { return *p; }
__device__ __forceinline__ float ldv(const bf16* p)   { return __bfloat162float(*p); }
__device__ __forceinline__ void  stv(float* p, float v) { *p = v; }
__device__ __forceinline__ void  stv(bf16* p,  float v) { *p = __float2bfloat16(v); }

__device__ __forceinline__ float sig_(float x) {
    return 1.0f / (1.0f + __expf(-x));
}
__device__ __forceinline__ float tanh_(float x) {
    float ax = fabsf(x);
    float e  = __expf(-2.0f * ax);
    float t  = (1.0f - e) / (1.0f + e);
    return x < 0.0f ? -t : t;
}

// ---- prep: fold input projection into layer-1 weights; combine biases ----
__global__ void prep_kernel(const float* __restrict__ wp, const float* __restrict__ bp,
                            const float* __restrict__ w_ih1f, const float* __restrict__ b_ih1f, const float* __restrict__ b_hh1f,
                            const float* __restrict__ w_ih1b, const float* __restrict__ b_ih1b, const float* __restrict__ b_hh1b,
                            const float* __restrict__ b_ih2f, const float* __restrict__ b_hh2f,
                            const float* __restrict__ b_ih2b, const float* __restrict__ b_hh2b,
                            float* __restrict__ w_eff1, float* __restrict__ b_eff1,
                            float* __restrict__ b_eff2) {
    int tid = blockIdx.x * blockDim.x + threadIdx.x;
    if (tid < 2 * RR) {
        int dir = tid / RR, r = tid % RR;
        const float* w_ih = dir ? w_ih1b : w_ih1f;
        const float* bi   = dir ? b_ih1b : b_ih1f;
        const float* bh   = dir ? b_hh1b : b_hh1f;
        const float* row  = w_ih + (long)r * DD;
        float acc[FEAT];
#pragma unroll
        for (int k = 0; k < FEAT; ++k) acc[k] = 0.0f;
        float bacc = bi[r] + bh[r];
        for (int d = 0; d < DD; ++d) {
            float w = row[d];
            bacc = fmaf(w, bp[d], bacc);
#pragma unroll
            for (int k = 0; k < FEAT; ++k) acc[k] = fmaf(w, wp[d * FEAT + k], acc[k]);
        }
#pragma unroll
        for (int k = 0; k < FEAT; ++k) w_eff1[(long)tid * FEAT + k] = acc[k];
        b_eff1[tid] = bacc;
    } else if (tid < 4 * RR) {
        int j = tid - 2 * RR;
        int dir = j / RR, r = j % RR;
        b_eff2[j] = dir ? (b_ih2b[r] + b_hh2b[r]) : (b_ih2f[r] + b_hh2f[r]);
    }
}

// ---- one bidirectional LSTM layer: one block per (dir,batch) chain ----
// 2 threads per gate-row (344 workers of 384): each holds HALF of the padded
// concatenated [x;h] weight vector in VGPRs; combine via __shfl_xor(z,1).
// Gate activations applied by the even thread before barrier 2.
template <int KI, typename TIN, typename TOUT>
__global__ __launch_bounds__(384, 3) void lstm_kernel(
        const TIN* __restrict__ in,        // [B][T][KI]
        const float* __restrict__ w_ih_f,  // [RR][KI]
        const float* __restrict__ w_hh_f,  // [RR][DD]
        const float* __restrict__ bias_f,  // [RR] (combined)
        const float* __restrict__ w_ih_b,
        const float* __restrict__ w_hh_b,
        const float* __restrict__ bias_b,
        TOUT* __restrict__ out)            // [B][T][2*DD]
{
    constexpr int K    = KI + DD;          // concatenated [x;h] length
    constexpr int K4   = (K + 3) / 4;      // float4 groups
    constexpr int H0   = (K4 + 1) / 2;     // groups for even thread (>= odd's)
    constexpr int KPAD = 8 * H0;           // padded buffer length (floats)

    const int bid = blockIdx.x;
    const int dir = bid & 1;
    const int b   = bid >> 1;
    const int tid = threadIdx.x;

    const float* w_ih = dir ? w_ih_b : w_ih_f;
    const float* w_hh = dir ? w_hh_b : w_hh_f;
    const float* bias = dir ? bias_b : bias_f;

    __shared__ __align__(16) float sbuf[2][KPAD];  // [0..KI)=x_t, [KI..K)=h, rest 0
    __shared__ float zbuf[RR];

    const int r  = tid >> 1;        // gate row
    const int hf = tid & 1;         // which half of K
    const int g0 = hf ? H0 : 0;
    const int gN = hf ? (K4 - H0) : H0;

    float w[4 * H0];
    float bsum = 0.0f, c = 0.0f;
    if (tid < 2 * RR) {
#pragma unroll
        for (int g = 0; g < H0; ++g) {
#pragma unroll
            for (int j = 0; j < 4; ++j) {
                int k = 4 * (g0 + g) + j;
                float v = 0.0f;
                if (g < gN && k < K)
                    v = (k < KI) ? w_ih[(long)r * KI + k]
                                 : w_hh[(long)r * DD + (k - KI)];
                w[4 * g + j] = v;
            }
        }
        if (hf == 0) bsum = bias[r];
    }
    // zero h region (initial h=0) and padding, both buffers
    for (int k = KI + tid; k < KPAD; k += 384) {
        sbuf[0][k] = 0.0f;
        sbuf[1][k] = 0.0f;
    }

    const long t0  = dir ? (TT - 1) : 0;
    const int  stp = dir ? -1 : 1;

    float xnext = 0.0f;
    if (tid < KI) xnext = ldv(in + ((long)b * TT + t0) * KI + tid);

    TOUT* outp = out + (long)b * TT * (2 * DD) + dir * DD;

    __syncthreads();

    long t = t0;
    for (int s = 0; s < TT; ++s) {
        const int cur = s & 1, nxt = cur ^ 1;
        if (tid < KI) sbuf[cur][tid] = xnext;
        __syncthreads();

        // prefetch next timestep's x (latency hidden under this step)
        const long tn = t + stp;
        if (s + 1 < TT && tid < KI) xnext = ldv(in + ((long)b * TT + tn) * KI + tid);

        if (tid < 2 * RR) {
            const float4* sv = reinterpret_cast<const float4*>(&sbuf[cur][0]) + g0;
            float a0 = bsum, a1 = 0.0f, a2 = 0.0f, a3 = 0.0f;
#pragma unroll
            for (int g = 0; g < H0; ++g) {
                float4 xv = sv[g];
                a0 = fmaf(w[4 * g + 0], xv.x, a0);
                a1 = fmaf(w[4 * g + 1], xv.y, a1);
                a2 = fmaf(w[4 * g + 2], xv.z, a2);
                a3 = fmaf(w[4 * g + 3], xv.w, a3);
            }
            float z = (a0 + a1) + (a2 + a3);
            z += __shfl_xor(z, 1);
            if (hf == 0) {
                // gate order i,f,g,o: rows [2DD,3DD) use tanh, rest sigmoid
                float act = (r >= 2 * DD && r < 3 * DD) ? tanh_(z) : sig_(z);
                zbuf[r] = act;
            }
        }
        __syncthreads();

        if (tid < DD) {
            float ig = zbuf[tid];
            float fg = zbuf[tid + DD];
            float gg = zbuf[tid + 2 * DD];
            float og = zbuf[tid + 3 * DD];
            c = fmaf(fg, c, ig * gg);
            float h = og * tanh_(c);
            sbuf[nxt][KI + tid] = h;           // h for next step
            stv(&outp[t * (2 * DD) + tid], h);
        }
        t = tn;
    }
}

// ---- dense head: per (b,t): 86 -> 30 -> 20 -> 1 ----
template <typename TIN>
__global__ void head_kernel(const TIN* __restrict__ h2,   // [BT][2*DD]
                            const float* __restrict__ w1, const float* __restrict__ b1,
                            const float* __restrict__ w2, const float* __restrict__ b2,
                            const float* __restrict__ w3, const float* __restrict__ b3,
                            float* __restrict__ outp) {
    long bt = (long)blockIdx.x * blockDim.x + threadIdx.x;
    if (bt >= (long)BB * TT) return;
    float v[2 * DD];
    const TIN* src = h2 + bt * (2 * DD);
#pragma unroll
    for (int k = 0; k < 2 * DD; ++k) v[k] = ldv(&src[k]);

    float m1[NH1];
#pragma unroll
    for (int j = 0; j < NH1; ++j) {
        float a = b1[j];
        const float* w = w1 + j * (2 * DD);
#pragma unroll
        for (int k = 0; k < 2 * DD; ++k) a = fmaf(w[k], v[k], a);
        m1[j] = fmaxf(a, 0.0f);
    }
    float m2[NH2];
#pragma unroll
    for (int j = 0; j < NH2; ++j) {
        float a = b2[j];
        const float* w = w2 + j * NH1;
#pragma unroll
        for (int k = 0; k < NH1; ++k) a = fmaf(w[k], m1[k], a);
        m2[j] = fmaxf(a, 0.0f);
    }
    float a = b3[0];
#pragma unroll
    for (int k = 0; k < NH2; ++k) a = fmaf(w3[k], m2[k], a);
    outp[bt] = a;
}

extern "C" void kernel_launch(void* const* d_in, const int* in_sizes, int n_in,
                              void* d_out, int out_size, void* d_ws, size_t ws_size,
                              hipStream_t stream) {
    const float* x      = (const float*)d_in[0];
    const float* w_proj = (const float*)d_in[1];
    const float* b_proj = (const float*)d_in[2];
    const float* w_ih1f = (const float*)d_in[3];
    const float* w_hh1f = (const float*)d_in[4];
    const float* b_ih1f = (const float*)d_in[5];
    const float* b_hh1f = (const float*)d_in[6];
    const float* w_ih1b = (const float*)d_in[7];
    const float* w_hh1b = (const float*)d_in[8];
    const float* b_ih1b = (const float*)d_in[9];
    const float* b_hh1b = (const float*)d_in[10];
    const float* w_ih2f = (const float*)d_in[11];
    const float* w_hh2f = (const float*)d_in[12];
    const float* b_ih2f = (const float*)d_in[13];
    const float* b_hh2f = (const float*)d_in[14];
    const float* w_ih2b = (const float*)d_in[15];
    const float* w_hh2b = (const float*)d_in[16];
    const float* b_ih2b = (const float*)d_in[17];
    const float* b_hh2b = (const float*)d_in[18];
    const float* w_d1   = (const float*)d_in[19];
    const float* b_d1   = (const float*)d_in[20];
    const float* w_d2   = (const float*)d_in[21];
    const float* b_d2   = (const float*)d_in[22];
    const float* w_out  = (const float*)d_in[23];
    const float* b_out  = (const float*)d_in[24];
    (void)in_sizes; (void)n_in; (void)out_size;

    // --- workspace layout ---
    float* w_eff1 = (float*)d_ws;
    float* b_eff1 = w_eff1 + 2 * RR * FEAT;
    float* b_eff2 = b_eff1 + 2 * RR;
    char*  big    = (char*)d_ws + 16384;
    size_t avail  = ws_size > 16384 ? ws_size - 16384 : 0;

    const size_t n1 = (size_t)BB * TT * 2 * DD;        // elems of out1/out2
    const size_t f1 = n1 * sizeof(float);              // 180.4 MB
    const size_t h1 = n1 * sizeof(bf16);               // 90.2 MB

    int tier;
    if      (avail >= f1 + f1) tier = 0;
    else if (avail >= f1 + h1) tier = 1;
    else                       tier = 2;

    prep_kernel<<<(4 * RR + 191) / 192, 192, 0, stream>>>(
        w_proj, b_proj,
        w_ih1f, b_ih1f, b_hh1f, w_ih1b, b_ih1b, b_hh1b,
        b_ih2f, b_hh2f, b_ih2b, b_hh2b,
        w_eff1, b_eff1, b_eff2);

    const float* weff_f = w_eff1;
    const float* weff_b = w_eff1 + (size_t)RR * FEAT;
    const float* be1_f  = b_eff1;
    const float* be1_b  = b_eff1 + RR;
    const float* be2_f  = b_eff2;
    const float* be2_b  = b_eff2 + RR;
    const int head_blocks = (int)(((long)BB * TT + 255) / 256);

    if (tier == 0) {
        float* out1 = (float*)big;
        float* out2 = (float*)(big + f1);
        lstm_kernel<FEAT, float, float><<<2 * BB, 384, 0, stream>>>(
            x, weff_f, w_hh1f, be1_f, weff_b, w_hh1b, be1_b, out1);
        lstm_kernel<2 * DD, float, float><<<2 * BB, 384, 0, stream>>>(
            out1, w_ih2f, w_hh2f, be2_f, w_ih2b, w_hh2b, be2_b, out2);
        head_kernel<float><<<head_blocks, 256, 0, stream>>>(
            out2, w_d1, b_d1, w_d2, b_d2, w_out, b_out, (float*)d_out);
    } else if (tier == 1) {
        float* out1 = (float*)big;
        bf16*  out2 = (bf16*)(big + f1);
        lstm_kernel<FEAT, float, float><<<2 * BB, 384, 0, stream>>>(
            x, weff_f, w_hh1f, be1_f, weff_b, w_hh1b, be1_b, out1);
        lstm_kernel<2 * DD, float, bf16><<<2 * BB, 384, 0, stream>>>(
            out1, w_ih2f, w_hh2f, be2_f, w_ih2b, w_hh2b, be2_b, out2);
        head_kernel<bf16><<<head_blocks, 256, 0, stream>>>(
            out2, w_d1, b_d1, w_d2, b_d2, w_out, b_out, (float*)d_out);
    } else {
        bf16* out1 = (bf16*)big;
        bf16* out2 = (bf16*)(big + h1);
        lstm_kernel<FEAT, float, bf16><<<2 * BB, 384, 0, stream>>>(
            x, weff_f, w_hh1f, be1_f, weff_b, w_hh1b, be1_b, out1);
        lstm_kernel<2 * DD, bf16, bf16><<<2 * BB, 384, 0, stream>>>(
            out1, w_ih2f, w_hh2f, be2_f, w_ih2b, w_hh2b, be2_b, out2);
        head_kernel<bf16><<<head_blocks, 256, 0, stream>>>(
            out2, w_d1, b_d1, w_d2, b_d2, w_out, b_out, (float*)d_out);
    }
}